// Round 6
// baseline (270.862 us; speedup 1.0000x reference)
//
#include <hip/hip_runtime.h>
#include <hip/hip_bf16.h>

// B=2, L=4096, D=1024, E=3072, FW=64. Only streams 0 and 2 of the expansion
// are ever used by the reference recurrence; stream 1 is skipped entirely.

typedef __bf16 bf16x8 __attribute__((ext_vector_type(8)));
typedef float  f32x4  __attribute__((ext_vector_type(4)));

typedef const __attribute__((address_space(1))) unsigned int GU32;
typedef __attribute__((address_space(3))) unsigned int LU32;
#define GLL16(gp, lp) __builtin_amdgcn_global_load_lds((GU32*)(gp), (LU32*)(lp), 16, 0, 0)

#define CFENCE asm volatile("" ::: "memory")
#define SBAR   do { CFENCE; __builtin_amdgcn_s_barrier(); CFENCE; } while (0)
#define SCHEDB __builtin_amdgcn_sched_barrier(0)
#define VMCNT8 asm volatile("s_waitcnt vmcnt(8)" ::: "memory")
#define VMCNT0 asm volatile("s_waitcnt vmcnt(0)" ::: "memory")

__device__ __forceinline__ float silu(float x) { return x / (1.f + __expf(-x)); }

// ---------------- K0: filter taps h[j] = filters[0, j] ----------------
// t[0] == 0 exactly => pos@w1 == 0, exp factor == 1. Fully general in b1/b2/w2/w3.
__global__ __launch_bounds__(256) void hgen(const float* __restrict__ b1,
                                            const float* __restrict__ w2,
                                            const float* __restrict__ b2,
                                            const float* __restrict__ w3,
                                            float* __restrict__ h) {
    __shared__ float hm2[64];
    int t = threadIdx.x;
    if (t < 64) {
        float acc = b2[t];
        for (int f = 0; f < 64; ++f) acc += silu(b1[f]) * w2[f * 64 + t];
        hm2[t] = silu(acc);
    }
    __syncthreads();
    for (int r = 0; r < 4; ++r) {
        int j = t * 4 + r;   // 0..1023
        float acc = 0.f;
        for (int g = 0; g < 64; ++g) acc += hm2[g] * w3[g * 1024 + j];
        h[j] = acc;
    }
}

// ---------------- K0b: banded-Toeplitz filter blocks in MFMA A-fragment order -
__global__ void hfrag(const float* __restrict__ h, __bf16* __restrict__ af) {
    int sp = blockIdx.x;      // 0..32
    int lane = threadIdx.x;   // 0..63
    int m = lane & 15, kh = lane >> 4;
    bf16x8 v;
    #pragma unroll
    for (int j = 0; j < 8; ++j) {
        int k = kh * 8 + j;
        int idx = (k < 16) ? (32 * sp + m - k) : (32 * sp + 32 + m - k);
        float val = (idx >= 0 && idx < 1024) ? h[idx] : 0.f;
        v[j] = (__bf16)val;
    }
    *(bf16x8*)&af[(size_t)(sp * 64 + lane) * 8] = v;
}

// ---------------- P0a: x f32 -> bf16 (vectorized elementwise) ----------------
__global__ __launch_bounds__(256) void cvt_x(const float* __restrict__ x,
                                             __bf16* __restrict__ xb) {
    size_t i = ((size_t)blockIdx.x * 256 + threadIdx.x) * 8;
    f32x4 a = *(const f32x4*)&x[i];
    f32x4 b = *(const f32x4*)&x[i + 4];
    bf16x8 v;
    v[0] = (__bf16)a[0]; v[1] = (__bf16)a[1]; v[2] = (__bf16)a[2]; v[3] = (__bf16)a[3];
    v[4] = (__bf16)b[0]; v[5] = (__bf16)b[1]; v[6] = (__bf16)b[2]; v[7] = (__bf16)b[3];
    *(bf16x8*)&xb[i] = v;
}

// ---------------- P0b: transpose+convert weight panel to [N][K] bf16 ----------
__global__ __launch_bounds__(256) void tcvt(const float* __restrict__ src,
                                            __bf16* __restrict__ dst,
                                            int ld, int cbase) {
    __shared__ __bf16 tile[64][65];
    int t = threadIdx.x;
    int k0 = blockIdx.x * 64, n0 = blockIdx.y * 64;
    int c = t & 63, rg = t >> 6;
    #pragma unroll
    for (int i = 0; i < 16; ++i) {
        int r = rg * 16 + i;
        tile[r][c] = (__bf16)src[(size_t)(k0 + r) * ld + cbase + n0 + c];
    }
    __syncthreads();
    #pragma unroll
    for (int i = 0; i < 16; ++i) {
        int nn = rg * 16 + i;
        dst[(size_t)(n0 + nn) * 1024 + k0 + c] = tile[c][nn];
    }
}

// ================= gemm256: 256x256-tile 8-phase GEMM (T2+T3+T4+T5) ===========
// C[M][N] = A[M][1024] @ Bt[N][1024]^T, bf16 in, dual-bf16 out split at col 1024.
// 512 threads = 8 waves (2M x 4N); per-wave C = 128x64. BK=64, 16 K-tiles.
// LDS 128KB = 2 dbuf x (A 2x16KB + B 2x16KB halves).
// T4 (counted vmcnt, the m218 lever): tile t+2's halves are staged into buf
// (t&1) as its slots die -- B-halves in t.P2 (B last read t.P1), A-halves in
// t.P3 (A last read t.P2); each stage is a full barrier after the slot's last
// reader (WAR-safe). Boundary wait = vmcnt(8): waits only tile t+1's 8 loads
// (issued 5-6 phases earlier, ~1000+ cyc old -> no stall), leaves tile t+2's
// 8 in flight. vmcnt(0) only once, in the no-prefetch tail (kt=14).
// T2 (full swizzle, rule-21 both-sides): LDS chunk c holds source chunk
// c ^ ((c>>3)&7) (involutive), read addr ^= (addr>>3)&0x70 -- spreads the
// 16 stride-128B rows of a ds_read_b128 group across all 32 banks (~2-way).
__device__ __forceinline__ void stage_half(const __bf16* __restrict__ panel, int kk,
                                           char* ldshalf, int t) {
    int c1 = t, c2 = t + 512;
    int s1 = c1 ^ ((c1 >> 3) & 7);
    int s2 = c2 ^ ((c2 >> 3) & 7);
    GLL16(panel + (size_t)(s1 >> 3) * 1024 + kk + (s1 & 7) * 8, ldshalf + c1 * 16);
    GLL16(panel + (size_t)(s2 >> 3) * 1024 + kk + (s2 & 7) * 8, ldshalf + c2 * 16);
}

__global__ __launch_bounds__(512, 1) void gemm256(const __bf16* __restrict__ A,
                                                  const __bf16* __restrict__ Bt,
                                                  const float* __restrict__ bias,
                                                  __bf16* __restrict__ out0,
                                                  __bf16* __restrict__ out1) {
    __shared__ __bf16 lds[65536];          // 128 KB
    char* L = (char*)lds;
    int t = threadIdx.x, lane = t & 63, w = t >> 6;
    int wr = w >> 2, wc = w & 3;           // wave tile: rows wr*128, cols wc*64
    int m0 = blockIdx.x * 256, n0 = blockIdx.y * 256;
    int rl = lane & 15, kh8 = (lane >> 4) * 8;
    int nloc = (wc & 1) * 64;

    const __bf16* pa0 = A + (size_t)m0 * 1024;
    const __bf16* pa1 = A + (size_t)(m0 + 128) * 1024;
    const __bf16* pb0 = Bt + (size_t)n0 * 1024;
    const __bf16* pb1 = Bt + (size_t)(n0 + 128) * 1024;

    f32x4 acc[8][4] = {};
    bf16x8 ar[4][2], br[4][2];

#define RDA(dst, mf, ks) do { int _a = bA + ((mf) * 16 + rl) * 128 + ((ks) * 32 + kh8) * 2; \
        _a ^= (_a >> 3) & 0x70; dst = *(const bf16x8*)(L + _a); } while (0)
#define RDB(dst, nf, ks) do { int _a = bB + (nloc + (nf) * 16 + rl) * 128 + ((ks) * 32 + kh8) * 2; \
        _a ^= (_a >> 3) & 0x70; dst = *(const bf16x8*)(L + _a); } while (0)

    // prologue: stage K-tiles 0 (buf0) and 1 (buf1); issue order makes the
    // oldest 8 loads = tile 0's, so vmcnt(8) waits exactly tile 0.
    stage_half(pb0, 0, L + 65536, t);
    stage_half(pb1, 0, L + 65536 + 16384, t);
    stage_half(pa0, 0, L, t);
    stage_half(pa1, 0, L + 16384, t);
    stage_half(pb0, 64, L + 65536 + 32768, t);
    stage_half(pb1, 64, L + 65536 + 32768 + 16384, t);
    stage_half(pa0, 64, L + 32768, t);
    stage_half(pa1, 64, L + 32768 + 16384, t);
    VMCNT8;
    SBAR;

    for (int kt = 0; kt < 16; ++kt) {
        int p = kt & 1;
        int bA = p * 32768 + wr * 16384;
        int bB = 65536 + p * 32768 + (wc >> 1) * 16384;
        int kk2 = (kt + 2) * 64;
        char* LA = L + p * 32768;                 // tile kt+2 shares parity with kt
        char* LB = L + 65536 + p * 32768;

        // ---- P0: read A(mf0-3)+B(nf0-1), both ks; MFMA Q00 ----
        #pragma unroll
        for (int i = 0; i < 4; ++i) { RDA(ar[i][0], i, 0); RDA(ar[i][1], i, 1); }
        RDB(br[0][0], 0, 0); RDB(br[0][1], 0, 1);
        RDB(br[1][0], 1, 0); RDB(br[1][1], 1, 1);
        SCHEDB; SBAR; SCHEDB;
        __builtin_amdgcn_s_setprio(1);
        #pragma unroll
        for (int mf = 0; mf < 4; ++mf)
            #pragma unroll
            for (int nf = 0; nf < 2; ++nf)
                #pragma unroll
                for (int ks = 0; ks < 2; ++ks)
                    acc[mf][nf] = __builtin_amdgcn_mfma_f32_16x16x32_bf16(ar[mf][ks], br[nf][ks], acc[mf][nf], 0, 0, 0);
        __builtin_amdgcn_s_setprio(0);
        SCHEDB; SBAR; SCHEDB;

        // ---- P1: read B(nf2-3); MFMA Q01.  (B slots of buf p die here) ----
        RDB(br[2][0], 2, 0); RDB(br[2][1], 2, 1);
        RDB(br[3][0], 3, 0); RDB(br[3][1], 3, 1);
        SCHEDB; SBAR; SCHEDB;
        __builtin_amdgcn_s_setprio(1);
        #pragma unroll
        for (int mf = 0; mf < 4; ++mf)
            #pragma unroll
            for (int nf = 2; nf < 4; ++nf)
                #pragma unroll
                for (int ks = 0; ks < 2; ++ks)
                    acc[mf][nf] = __builtin_amdgcn_mfma_f32_16x16x32_bf16(ar[mf][ks], br[nf][ks], acc[mf][nf], 0, 0, 0);
        __builtin_amdgcn_s_setprio(0);
        SCHEDB; SBAR; SCHEDB;

        // ---- P2: read A(mf4-7); stage tile kt+2 B-halves; MFMA Q10 ----
        #pragma unroll
        for (int i = 0; i < 4; ++i) { RDA(ar[i][0], 4 + i, 0); RDA(ar[i][1], 4 + i, 1); }
        if (kt < 14) {
            stage_half(pb0, kk2, LB, t);
            stage_half(pb1, kk2, LB + 16384, t);
        }
        SCHEDB; SBAR; SCHEDB;
        __builtin_amdgcn_s_setprio(1);
        #pragma unroll
        for (int mf = 0; mf < 4; ++mf)
            #pragma unroll
            for (int nf = 0; nf < 2; ++nf)
                #pragma unroll
                for (int ks = 0; ks < 2; ++ks)
                    acc[4 + mf][nf] = __builtin_amdgcn_mfma_f32_16x16x32_bf16(ar[mf][ks], br[nf][ks], acc[4 + mf][nf], 0, 0, 0);
        __builtin_amdgcn_s_setprio(0);
        SCHEDB; SBAR; SCHEDB;

        // ---- P3: stage tile kt+2 A-halves; MFMA Q11; counted boundary wait ----
        if (kt < 14) {
            stage_half(pa0, kk2, LA, t);
            stage_half(pa1, kk2, LA + 16384, t);
        }
        SCHEDB; SBAR; SCHEDB;
        __builtin_amdgcn_s_setprio(1);
        #pragma unroll
        for (int mf = 0; mf < 4; ++mf)
            #pragma unroll
            for (int nf = 2; nf < 4; ++nf)
                #pragma unroll
                for (int ks = 0; ks < 2; ++ks)
                    acc[4 + mf][nf] = __builtin_amdgcn_mfma_f32_16x16x32_bf16(ar[mf][ks], br[nf][ks], acc[4 + mf][nf], 0, 0, 0);
        __builtin_amdgcn_s_setprio(0);
        if (kt < 14)      { VMCNT8; }   // waits tile kt+1's 8 loads (5-6 phases old)
        else if (kt == 14){ VMCNT0; }   // tail: tile 15's loads (no new issues)
        SCHEDB; SBAR; SCHEDB;
    }
#undef RDA
#undef RDB

    int cb = lane & 15, rb = (lane >> 4) * 4;
    #pragma unroll
    for (int nf = 0; nf < 4; ++nf) {
        int col = n0 + wc * 64 + nf * 16 + cb;
        __bf16* uo = (col < 1024) ? out0 : out1;
        int oc = col & 1023;
        float bv = bias[(col < 1024) ? col : 1024 + col];
        #pragma unroll
        for (int mf = 0; mf < 8; ++mf) {
            int row = m0 + wr * 128 + mf * 16 + rb;
            #pragma unroll
            for (int j = 0; j < 4; ++j)
                uo[(size_t)(row + j) * 1024 + oc] = (__bf16)(acc[mf][nf][j] + bv);
        }
    }
}

// ---------------- m97-structure 128x128 GEMM (kept for gemm2) -----------------
template<int EPI>
__global__ __launch_bounds__(256) void gemm128(const __bf16* __restrict__ A,
                                               const __bf16* __restrict__ Bt,
                                               const float* __restrict__ bias,
                                               void* __restrict__ out0,
                                               void* __restrict__ out1) {
    __shared__ __bf16 As[128 * 32];
    __shared__ __bf16 Bs[128 * 32];
    int t = threadIdx.x, lane = t & 63, w = t >> 6;
    int m0 = blockIdx.x * 128, n0 = blockIdx.y * 128;
    int wr = (w >> 1) * 64, wc = (w & 1) * 64;
    f32x4 acc[4][4] = {};

    int s1 = w * 64 + lane;
    int s2 = s1 + 256;
    const __bf16* a1 = A + (size_t)(m0 + (s1 >> 2)) * 1024 + (s1 & 3) * 8;
    const __bf16* a2 = A + (size_t)(m0 + (s2 >> 2)) * 1024 + (s2 & 3) * 8;
    const __bf16* b1 = Bt + (size_t)(n0 + (s1 >> 2)) * 1024 + (s1 & 3) * 8;
    const __bf16* b2 = Bt + (size_t)(n0 + (s2 >> 2)) * 1024 + (s2 & 3) * 8;

    for (int kk = 0; kk < 1024; kk += 32) {
        GLL16(a1 + kk, (char*)&As[(size_t)s1 * 8]);
        GLL16(a2 + kk, (char*)&As[(size_t)s2 * 8]);
        GLL16(b1 + kk, (char*)&Bs[(size_t)s1 * 8]);
        GLL16(b2 + kk, (char*)&Bs[(size_t)s2 * 8]);
        __syncthreads();
        int kh = (lane >> 4) * 8, rl = lane & 15;
        bf16x8 af[4], bf[4];
        #pragma unroll
        for (int i = 0; i < 4; ++i) {
            af[i] = *(const bf16x8*)&As[(wr + i * 16 + rl) * 32 + kh];
            bf[i] = *(const bf16x8*)&Bs[(wc + i * 16 + rl) * 32 + kh];
        }
        #pragma unroll
        for (int mi = 0; mi < 4; ++mi)
            #pragma unroll
            for (int ni = 0; ni < 4; ++ni)
                acc[mi][ni] = __builtin_amdgcn_mfma_f32_16x16x32_bf16(af[mi], bf[ni], acc[mi][ni], 0, 0, 0);
        __syncthreads();
    }

    int cb = lane & 15, rb = (lane >> 4) * 4;
    #pragma unroll
    for (int ni = 0; ni < 4; ++ni) {
        int col = n0 + wc + ni * 16 + cb;
        if (EPI == 0) {
            __bf16* uo = (col < 1024) ? (__bf16*)out0 : (__bf16*)out1;
            int oc = col & 1023;
            float bv = bias[(col < 1024) ? col : 1024 + col];
            #pragma unroll
            for (int mi = 0; mi < 4; ++mi) {
                int row = m0 + wr + mi * 16 + rb;
                #pragma unroll
                for (int j = 0; j < 4; ++j)
                    uo[(size_t)(row + j) * 1024 + oc] = (__bf16)(acc[mi][ni][j] + bv);
            }
        } else {
            float* o = (float*)out0;
            float bv = bias[col];
            #pragma unroll
            for (int mi = 0; mi < 4; ++mi) {
                int row = m0 + wr + mi * 16 + rb;
                #pragma unroll
                for (int j = 0; j < 4; ++j)
                    o[(size_t)(row + j) * 1024 + col] = acc[mi][ni][j] + bv;
            }
        }
    }
}

// ---------------- K2: depthwise conv + gating; v->[B,D,L], s0->[B,L,D] --------
__global__ __launch_bounds__(256) void convmul(const __bf16* __restrict__ u0,
                                               const __bf16* __restrict__ u2,
                                               const float* __restrict__ w_conv,
                                               const float* __restrict__ b_conv,
                                               __bf16* __restrict__ v,
                                               __bf16* __restrict__ st) {
    __shared__ float vt[64][65];
    int t = threadIdx.x;
    int b = blockIdx.z;
    int l0b = blockIdx.x * 64;
    int d0 = blockIdx.y * 64;
    int d = t & 63, lg = t >> 6;
    int col = d0 + d;
    int l0 = l0b + lg * 16;

    float c00 = w_conv[col * 3 + 0], c01 = w_conv[col * 3 + 1], c02 = w_conv[col * 3 + 2];
    float bc0 = b_conv[col];
    int e2 = 2048 + col;
    float c20 = w_conv[e2 * 3 + 0], c21 = w_conv[e2 * 3 + 1], c22 = w_conv[e2 * 3 + 2];
    float bc2 = b_conv[e2];

    size_t base = ((size_t)b * 4096 + l0) * 1024 + col;
    float p01 = (l0 >= 1) ? (float)u0[base - 1024] : 0.f;
    float p02 = (l0 >= 2) ? (float)u0[base - 2048] : 0.f;
    float p21 = (l0 >= 1) ? (float)u2[base - 1024] : 0.f;
    float p22 = (l0 >= 2) ? (float)u2[base - 2048] : 0.f;
    #pragma unroll
    for (int il = 0; il < 16; ++il) {
        float c0v = (float)u0[base + (size_t)il * 1024];
        float c2v = (float)u2[base + (size_t)il * 1024];
        float s0v = c00 * p02 + c01 * p01 + c02 * c0v + bc0;
        float s2v = c20 * p22 + c21 * p21 + c22 * c2v + bc2;
        p02 = p01; p01 = c0v; p22 = p21; p21 = c2v;
        vt[lg * 16 + il][d] = s0v * s2v;
        st[base + (size_t)il * 1024] = (__bf16)s0v;   // [B,L,D] direct, coalesced
    }
    __syncthreads();
    int lo = t & 63, dg = t >> 6;
    size_t obase = ((size_t)b * 1024 + d0 + dg * 16) * 4096 + l0b + lo;
    #pragma unroll
    for (int id = 0; id < 16; ++id)
        v[obase + (size_t)id * 4096] = (__bf16)vt[lo][dg * 16 + id];
}

// ---------------- K3: 1024-tap causal FIR via MFMA block-Toeplitz -------------
__global__ __launch_bounds__(256) void firk(const __bf16* __restrict__ v,
                                            const __bf16* __restrict__ afg,
                                            const float* __restrict__ filt_bias,
                                            __bf16* __restrict__ z) {
    __shared__ __bf16 vlds[768 * 8];       // chunks 0..129 zero-pad, 130..641 data
    __shared__ __bf16 alds[33 * 64 * 8];   // A-fragments, lane-contiguous
    int t = threadIdx.x;
    int bd = blockIdx.x;          // b*1024 + d
    int d = bd & 1023;
    const __bf16* vrow = v + (size_t)bd * 4096;

    for (int c = t; c < 33 * 64; c += 256)
        *(bf16x8*)&alds[c * 8] = *(const bf16x8*)&afg[(size_t)c * 8];
    #pragma unroll
    for (int i = 0; i < 3; ++i) {
        int c = t + i * 256;
        bf16x8 val = {};
        if (c >= 130 && c < 642) val = *(const bf16x8*)&vrow[(c - 130) * 8];
        int cs = c ^ ((c >> 3) & 7);
        *(bf16x8*)&vlds[cs * 8] = val;
    }
    __syncthreads();

    int lane = t & 63, w = t >> 6;
    int n = lane & 15, kh = lane >> 4;
    int khoff = (kh == 0) ? 0 : (kh == 1) ? 8 : (kh == 2) ? -16 : -8;
    f32x4 acc[4] = {};
    for (int sp = 0; sp < 33; ++sp) {
        bf16x8 af = *(const bf16x8*)&alds[(sp * 64 + lane) * 8];
        #pragma unroll
        for (int ct = 0; ct < 4; ++ct) {
            int p = w * 64 + ct * 16 + n;
            int e = 16 * p - 32 * sp + 1040 + khoff;   // vpad index, multiple of 8
            int c = e >> 3;
            int cs = c ^ ((c >> 3) & 7);
            bf16x8 bfv = *(const bf16x8*)&vlds[cs * 8];
            acc[ct] = __builtin_amdgcn_mfma_f32_16x16x32_bf16(af, bfv, acc[ct], 0, 0, 0);
        }
    }

    float fb = filt_bias[d];
    __bf16* zrow = z + (size_t)bd * 4096;
    #pragma unroll
    for (int ct = 0; ct < 4; ++ct) {
        int p = w * 64 + ct * 16 + n;
        #pragma unroll
        for (int j = 0; j < 4; ++j) {
            int l = 16 * p + kh * 4 + j;
            int e = l + 1040;
            int c = e >> 3;
            int cs = c ^ ((c >> 3) & 7);
            float vv = (float)vlds[cs * 8 + (e & 7)];
            zrow[l] = (__bf16)(acc[ct][j] + vv * fb);
        }
    }
}

// ---------------- K3b: transpose zz [B,D,L] -> [B,L,D] and gate by s0 ---------
__global__ __launch_bounds__(256) void trz(const __bf16* __restrict__ zz,
                                           const __bf16* __restrict__ st,
                                           __bf16* __restrict__ zt) {
    __shared__ __bf16 tile[64][65];
    int t = threadIdx.x;
    int l0 = blockIdx.x * 64, d0 = blockIdx.y * 64, b = blockIdx.z;
    int c = t & 63, rg = t >> 6;
    #pragma unroll
    for (int i = 0; i < 16; ++i) {
        int r = rg * 16 + i;
        tile[r][c] = zz[((size_t)(b * 1024 + d0 + r)) * 4096 + l0 + c];
    }
    __syncthreads();
    #pragma unroll
    for (int i = 0; i < 16; ++i) {
        int li = rg * 16 + i;
        size_t o = ((size_t)b * 4096 + l0 + li) * 1024 + d0 + c;
        zt[o] = (__bf16)((float)tile[c][li] * (float)st[o]);
    }
}

extern "C" void kernel_launch(void* const* d_in, const int* in_sizes, int n_in,
                              void* d_out, int out_size, void* d_ws, size_t ws_size,
                              hipStream_t stream) {
    const float* x      = (const float*)d_in[0];
    const float* w_in   = (const float*)d_in[1];
    const float* b_in   = (const float*)d_in[2];
    const float* w_conv = (const float*)d_in[3];
    const float* b_conv = (const float*)d_in[4];
    // d_in[5] = w1: multiplied by t[0]==0, mathematically unused for h
    const float* b1     = (const float*)d_in[6];
    const float* w2     = (const float*)d_in[7];
    const float* b2     = (const float*)d_in[8];
    const float* w3     = (const float*)d_in[9];
    const float* fb     = (const float*)d_in[10];
    const float* w_out  = (const float*)d_in[11];
    const float* b_out  = (const float*)d_in[12];
    float* out = (float*)d_out;

    // Workspace span = 40960 + 64 MB (round-1-proven bound), temporally aliased:
    //   X : xbf (P1) -> vv (P2-P3) -> wot (P5)
    //   U0: u0  (P1-P2) -> zt (P4-P5)
    //   U2: u2  (P1-P2) -> zz (P3-P4)
    //   ST: st  (P2...) ; WT overlaps ST's tail (WT dead before st written)
    char* ws = (char*)d_ws;
    float*  h  = (float*)ws;                          // 4 KB
    __bf16* af = (__bf16*)(ws + 4096);                // 33 KB
    const size_t SEG = (size_t)8192 * 1024;
    __bf16* X  = (__bf16*)(ws + 40960);
    __bf16* U0 = X + SEG;
    __bf16* U2 = U0 + SEG;
    __bf16* ST = U2 + SEG;
    __bf16* WT = ST + SEG - (size_t)2048 * 1024;      // [2048][1024] bf16, 4 MB

    hgen<<<1, 256, 0, stream>>>(b1, w2, b2, w3, h);
    hfrag<<<33, 64, 0, stream>>>(h, af);
    cvt_x<<<4096, 256, 0, stream>>>(x, X);
    tcvt<<<dim3(16, 16), 256, 0, stream>>>(w_in, WT, 3072, 0);
    tcvt<<<dim3(16, 16), 256, 0, stream>>>(w_in, WT + (size_t)1024 * 1024, 3072, 2048);
    gemm256<<<dim3(32, 8), 512, 0, stream>>>(X, WT, b_in, U0, U2);
    convmul<<<dim3(64, 16, 2), 256, 0, stream>>>(U0, U2, w_conv, b_conv, X, ST);
    firk<<<2048, 256, 0, stream>>>(X, af, fb, U2);
    tcvt<<<dim3(16, 16), 256, 0, stream>>>(w_out, X, 1024, 0);   // wot into X (vv dead)
    trz<<<dim3(64, 16, 2), 256, 0, stream>>>(U2, ST, U0);
    gemm128<1><<<dim3(64, 8), 256, 0, stream>>>(U0, X, b_out, (void*)out, nullptr);
}

// Round 7
// 242.893 us; speedup vs baseline: 1.1152x; 1.1152x over previous
//
#include <hip/hip_runtime.h>
#include <hip/hip_bf16.h>

// B=2, L=4096, D=1024, E=3072, FW=64. Only streams 0 and 2 of the expansion
// are ever used by the reference recurrence; stream 1 is skipped entirely.

typedef __bf16 bf16x8 __attribute__((ext_vector_type(8)));
typedef float  f32x4  __attribute__((ext_vector_type(4)));

typedef const __attribute__((address_space(1))) unsigned int GU32;
typedef __attribute__((address_space(3))) unsigned int LU32;
#define GLL16(gp, lp) __builtin_amdgcn_global_load_lds((GU32*)(gp), (LU32*)(lp), 16, 0, 0)

#define SBAR   __builtin_amdgcn_s_barrier()
#define VMCNT8 asm volatile("s_waitcnt vmcnt(8)" ::: "memory")
#define VMCNT0 asm volatile("s_waitcnt vmcnt(0)" ::: "memory")

__device__ __forceinline__ float silu(float x) { return x / (1.f + __expf(-x)); }

// ---------------- K0: filter taps h[j] = filters[0, j] + A-fragment pack ------
// t[0] == 0 exactly => pos@w1 == 0, exp factor == 1. Fully general in b1/b2/w2/w3.
// Merged hfrag: A_sp[m][k] = h[32sp+m-k] (k<16) / h[32sp+32+m-k] (k>=16),
// lane l holds A[m=l&15][k=(l>>4)*8+j].
__global__ __launch_bounds__(256) void hgen(const float* __restrict__ b1,
                                            const float* __restrict__ w2,
                                            const float* __restrict__ b2,
                                            const float* __restrict__ w3,
                                            __bf16* __restrict__ af) {
    __shared__ float hm2[64];
    __shared__ float hl[1024];
    int t = threadIdx.x;
    if (t < 64) {
        float acc = b2[t];
        for (int f = 0; f < 64; ++f) acc += silu(b1[f]) * w2[f * 64 + t];
        hm2[t] = silu(acc);
    }
    __syncthreads();
    for (int r = 0; r < 4; ++r) {
        int j = t * 4 + r;   // 0..1023
        float acc = 0.f;
        for (int g = 0; g < 64; ++g) acc += hm2[g] * w3[g * 1024 + j];
        hl[j] = acc;
    }
    __syncthreads();
    for (int c = t; c < 33 * 64; c += 256) {
        int sp = c >> 6, lane = c & 63;
        int m = lane & 15, kh = lane >> 4;
        bf16x8 v;
        #pragma unroll
        for (int j = 0; j < 8; ++j) {
            int k = kh * 8 + j;
            int idx = (k < 16) ? (32 * sp + m - k) : (32 * sp + 32 + m - k);
            float val = (idx >= 0 && idx < 1024) ? hl[idx] : 0.f;
            v[j] = (__bf16)val;
        }
        *(bf16x8*)&af[(size_t)c * 8] = v;
    }
}

// ---------------- P0a: x f32 -> bf16 (vectorized elementwise) ----------------
__global__ __launch_bounds__(256) void cvt_x(const float* __restrict__ x,
                                             __bf16* __restrict__ xb) {
    size_t i = ((size_t)blockIdx.x * 256 + threadIdx.x) * 8;
    f32x4 a = *(const f32x4*)&x[i];
    f32x4 b = *(const f32x4*)&x[i + 4];
    bf16x8 v;
    v[0] = (__bf16)a[0]; v[1] = (__bf16)a[1]; v[2] = (__bf16)a[2]; v[3] = (__bf16)a[3];
    v[4] = (__bf16)b[0]; v[5] = (__bf16)b[1]; v[6] = (__bf16)b[2]; v[7] = (__bf16)b[3];
    *(bf16x8*)&xb[i] = v;
}

// ---------------- P0b: transpose+convert weight panel to [N][K] bf16 ----------
__global__ __launch_bounds__(256) void tcvt(const float* __restrict__ src,
                                            __bf16* __restrict__ dst,
                                            int ld, int cbase) {
    __shared__ __bf16 tile[64][65];
    int t = threadIdx.x;
    int k0 = blockIdx.x * 64, n0 = blockIdx.y * 64;
    int c = t & 63, rg = t >> 6;
    #pragma unroll
    for (int i = 0; i < 16; ++i) {
        int r = rg * 16 + i;
        tile[r][c] = (__bf16)src[(size_t)(k0 + r) * ld + cbase + n0 + c];
    }
    __syncthreads();
    #pragma unroll
    for (int i = 0; i < 16; ++i) {
        int nn = rg * 16 + i;
        dst[(size_t)(n0 + nn) * 1024 + k0 + c] = tile[c][nn];
    }
}

// ================= gemm256: 256x256-tile phased GEMM (T2+T4+T5) ===============
// C[M][N] = A[M][1024] @ Bt[N][1024]^T, bf16 in, dual-bf16 out split at col 1024.
// 512 threads = 8 waves (2M x 4N); per-wave C = 128x64. BK=64, 16 K-tiles.
// LDS 128KB = 2 dbuf x (A 2x16KB + B 2x16KB halves). Tile kt reads buf p=kt&1;
// staging in kt.P2/P3 writes tile kt+2 into buf p, each half only after the
// barrier following its last reader (B dies after P1, A after P2) -- WAR-safe.
// Boundary wait vmcnt(8): waits only tile kt+1's 8 loads (5-6 phases old),
// leaves kt+2's 8 in flight. NO sched_barrier pins (m141: pinning regresses) --
// s_barrier + the asm memory clobber still order all memory ops; MFMA/VALU
// scheduling is left to the compiler.
__device__ __forceinline__ void stage_half(const __bf16* __restrict__ panel, int kk,
                                           char* ldshalf, int t) {
    int c1 = t, c2 = t + 512;
    int s1 = c1 ^ ((c1 >> 3) & 7);
    int s2 = c2 ^ ((c2 >> 3) & 7);
    GLL16(panel + (size_t)(s1 >> 3) * 1024 + kk + (s1 & 7) * 8, ldshalf + c1 * 16);
    GLL16(panel + (size_t)(s2 >> 3) * 1024 + kk + (s2 & 7) * 8, ldshalf + c2 * 16);
}

__global__ __launch_bounds__(512, 1) void gemm256(const __bf16* __restrict__ A,
                                                  const __bf16* __restrict__ Bt,
                                                  const float* __restrict__ bias,
                                                  __bf16* __restrict__ out0,
                                                  __bf16* __restrict__ out1) {
    __shared__ __bf16 lds[65536];          // 128 KB
    char* L = (char*)lds;
    int t = threadIdx.x, lane = t & 63, w = t >> 6;
    int wr = w >> 2, wc = w & 3;           // wave tile: rows wr*128, cols wc*64
    int m0 = blockIdx.x * 256, n0 = blockIdx.y * 256;
    int rl = lane & 15, kh8 = (lane >> 4) * 8;
    int nloc = (wc & 1) * 64;

    const __bf16* pa0 = A + (size_t)m0 * 1024;
    const __bf16* pa1 = A + (size_t)(m0 + 128) * 1024;
    const __bf16* pb0 = Bt + (size_t)n0 * 1024;
    const __bf16* pb1 = Bt + (size_t)(n0 + 128) * 1024;

    f32x4 acc[8][4] = {};
    bf16x8 ar[4][2], br[4][2];

#define RDA(dst, mf, ks) do { int _a = bA + ((mf) * 16 + rl) * 128 + ((ks) * 32 + kh8) * 2; \
        _a ^= (_a >> 3) & 0x70; dst = *(const bf16x8*)(L + _a); } while (0)
#define RDB(dst, nf, ks) do { int _a = bB + (nloc + (nf) * 16 + rl) * 128 + ((ks) * 32 + kh8) * 2; \
        _a ^= (_a >> 3) & 0x70; dst = *(const bf16x8*)(L + _a); } while (0)

    // prologue: stage K-tiles 0 (buf0) and 1 (buf1); oldest 8 = tile 0's.
    stage_half(pb0, 0, L + 65536, t);
    stage_half(pb1, 0, L + 65536 + 16384, t);
    stage_half(pa0, 0, L, t);
    stage_half(pa1, 0, L + 16384, t);
    stage_half(pb0, 64, L + 65536 + 32768, t);
    stage_half(pb1, 64, L + 65536 + 32768 + 16384, t);
    stage_half(pa0, 64, L + 32768, t);
    stage_half(pa1, 64, L + 32768 + 16384, t);
    VMCNT8;
    SBAR;

    for (int kt = 0; kt < 16; ++kt) {
        int p = kt & 1;
        int bA = p * 32768 + wr * 16384;
        int bB = 65536 + p * 32768 + (wc >> 1) * 16384;
        int kk2 = (kt + 2) * 64;
        char* LA = L + p * 32768;                 // tile kt+2 shares parity with kt
        char* LB = L + 65536 + p * 32768;

        // ---- P0: read A(mf0-3)+B(nf0-1), both ks; MFMA Q00 ----
        #pragma unroll
        for (int i = 0; i < 4; ++i) { RDA(ar[i][0], i, 0); RDA(ar[i][1], i, 1); }
        RDB(br[0][0], 0, 0); RDB(br[0][1], 0, 1);
        RDB(br[1][0], 1, 0); RDB(br[1][1], 1, 1);
        SBAR;
        __builtin_amdgcn_s_setprio(1);
        #pragma unroll
        for (int mf = 0; mf < 4; ++mf)
            #pragma unroll
            for (int nf = 0; nf < 2; ++nf)
                #pragma unroll
                for (int ks = 0; ks < 2; ++ks)
                    acc[mf][nf] = __builtin_amdgcn_mfma_f32_16x16x32_bf16(ar[mf][ks], br[nf][ks], acc[mf][nf], 0, 0, 0);
        __builtin_amdgcn_s_setprio(0);
        SBAR;

        // ---- P1: read B(nf2-3); MFMA Q01.  (B slots of buf p die here) ----
        RDB(br[2][0], 2, 0); RDB(br[2][1], 2, 1);
        RDB(br[3][0], 3, 0); RDB(br[3][1], 3, 1);
        SBAR;
        __builtin_amdgcn_s_setprio(1);
        #pragma unroll
        for (int mf = 0; mf < 4; ++mf)
            #pragma unroll
            for (int nf = 2; nf < 4; ++nf)
                #pragma unroll
                for (int ks = 0; ks < 2; ++ks)
                    acc[mf][nf] = __builtin_amdgcn_mfma_f32_16x16x32_bf16(ar[mf][ks], br[nf][ks], acc[mf][nf], 0, 0, 0);
        __builtin_amdgcn_s_setprio(0);
        SBAR;

        // ---- P2: read A(mf4-7); stage tile kt+2 B-halves; MFMA Q10 ----
        #pragma unroll
        for (int i = 0; i < 4; ++i) { RDA(ar[i][0], 4 + i, 0); RDA(ar[i][1], 4 + i, 1); }
        if (kt < 14) {
            stage_half(pb0, kk2, LB, t);
            stage_half(pb1, kk2, LB + 16384, t);
        }
        SBAR;
        __builtin_amdgcn_s_setprio(1);
        #pragma unroll
        for (int mf = 0; mf < 4; ++mf)
            #pragma unroll
            for (int nf = 0; nf < 2; ++nf)
                #pragma unroll
                for (int ks = 0; ks < 2; ++ks)
                    acc[4 + mf][nf] = __builtin_amdgcn_mfma_f32_16x16x32_bf16(ar[mf][ks], br[nf][ks], acc[4 + mf][nf], 0, 0, 0);
        __builtin_amdgcn_s_setprio(0);
        SBAR;

        // ---- P3: stage tile kt+2 A-halves; MFMA Q11; counted boundary wait ----
        if (kt < 14) {
            stage_half(pa0, kk2, LA, t);
            stage_half(pa1, kk2, LA + 16384, t);
        }
        SBAR;
        __builtin_amdgcn_s_setprio(1);
        #pragma unroll
        for (int mf = 0; mf < 4; ++mf)
            #pragma unroll
            for (int nf = 2; nf < 4; ++nf)
                #pragma unroll
                for (int ks = 0; ks < 2; ++ks)
                    acc[4 + mf][nf] = __builtin_amdgcn_mfma_f32_16x16x32_bf16(ar[mf][ks], br[nf][ks], acc[4 + mf][nf], 0, 0, 0);
        __builtin_amdgcn_s_setprio(0);
        if (kt < 14)      { VMCNT8; }   // waits tile kt+1's 8 loads (5-6 phases old)
        else if (kt == 14){ VMCNT0; }   // tail: tile 15's loads (no new issues)
        SBAR;
    }
#undef RDA
#undef RDB

    // Epilogue: row-major inner-nf so each output row's 128B line is completed
    // by 4 back-to-back stores (L2 merges partial lines -> less write amp).
    int cb = lane & 15, rb = (lane >> 4) * 4;
    int colb = n0 + wc * 64 + cb;
    __bf16* uo = (colb < 1024) ? out0 : out1;
    float bv[4];
    #pragma unroll
    for (int nf = 0; nf < 4; ++nf) {
        int col = colb + nf * 16;
        bv[nf] = bias[(col < 1024) ? col : 1024 + col];
    }
    #pragma unroll
    for (int mf = 0; mf < 8; ++mf)
        #pragma unroll
        for (int j = 0; j < 4; ++j) {
            size_t base = (size_t)(m0 + wr * 128 + mf * 16 + rb + j) * 1024;
            #pragma unroll
            for (int nf = 0; nf < 4; ++nf)
                uo[base + ((colb + nf * 16) & 1023)] = (__bf16)(acc[mf][nf][j] + bv[nf]);
        }
}

// ---------------- m97-structure 128x128 GEMM (gemm2, f32 out) -----------------
__global__ __launch_bounds__(256) void gemm128(const __bf16* __restrict__ A,
                                               const __bf16* __restrict__ Bt,
                                               const float* __restrict__ bias,
                                               float* __restrict__ out) {
    __shared__ __bf16 As[128 * 32];
    __shared__ __bf16 Bs[128 * 32];
    int t = threadIdx.x, lane = t & 63, w = t >> 6;
    int m0 = blockIdx.x * 128, n0 = blockIdx.y * 128;
    int wr = (w >> 1) * 64, wc = (w & 1) * 64;
    f32x4 acc[4][4] = {};

    int s1 = w * 64 + lane;
    int s2 = s1 + 256;
    const __bf16* a1 = A + (size_t)(m0 + (s1 >> 2)) * 1024 + (s1 & 3) * 8;
    const __bf16* a2 = A + (size_t)(m0 + (s2 >> 2)) * 1024 + (s2 & 3) * 8;
    const __bf16* b1 = Bt + (size_t)(n0 + (s1 >> 2)) * 1024 + (s1 & 3) * 8;
    const __bf16* b2 = Bt + (size_t)(n0 + (s2 >> 2)) * 1024 + (s2 & 3) * 8;

    for (int kk = 0; kk < 1024; kk += 32) {
        GLL16(a1 + kk, (char*)&As[(size_t)s1 * 8]);
        GLL16(a2 + kk, (char*)&As[(size_t)s2 * 8]);
        GLL16(b1 + kk, (char*)&Bs[(size_t)s1 * 8]);
        GLL16(b2 + kk, (char*)&Bs[(size_t)s2 * 8]);
        __syncthreads();
        int kh = (lane >> 4) * 8, rl = lane & 15;
        bf16x8 af[4], bf[4];
        #pragma unroll
        for (int i = 0; i < 4; ++i) {
            af[i] = *(const bf16x8*)&As[(wr + i * 16 + rl) * 32 + kh];
            bf[i] = *(const bf16x8*)&Bs[(wc + i * 16 + rl) * 32 + kh];
        }
        #pragma unroll
        for (int mi = 0; mi < 4; ++mi)
            #pragma unroll
            for (int ni = 0; ni < 4; ++ni)
                acc[mi][ni] = __builtin_amdgcn_mfma_f32_16x16x32_bf16(af[mi], bf[ni], acc[mi][ni], 0, 0, 0);
        __syncthreads();
    }

    int cb = lane & 15, rb = (lane >> 4) * 4;
    float bv[4];
    #pragma unroll
    for (int ni = 0; ni < 4; ++ni) bv[ni] = bias[n0 + wc + ni * 16 + cb];
    #pragma unroll
    for (int mi = 0; mi < 4; ++mi)
        #pragma unroll
        for (int j = 0; j < 4; ++j) {
            size_t base = (size_t)(m0 + wr + mi * 16 + rb + j) * 1024 + n0 + wc + cb;
            #pragma unroll
            for (int ni = 0; ni < 4; ++ni)
                out[base + ni * 16] = acc[mi][ni][j] + bv[ni];
        }
}

// ---------------- K2: depthwise conv + gating; v->[B,D,L], s0->[B,L,D] --------
__global__ __launch_bounds__(256) void convmul(const __bf16* __restrict__ u0,
                                               const __bf16* __restrict__ u2,
                                               const float* __restrict__ w_conv,
                                               const float* __restrict__ b_conv,
                                               __bf16* __restrict__ v,
                                               __bf16* __restrict__ st) {
    __shared__ float vt[64][65];
    int t = threadIdx.x;
    int b = blockIdx.z;
    int l0b = blockIdx.x * 64;
    int d0 = blockIdx.y * 64;
    int d = t & 63, lg = t >> 6;
    int col = d0 + d;
    int l0 = l0b + lg * 16;

    float c00 = w_conv[col * 3 + 0], c01 = w_conv[col * 3 + 1], c02 = w_conv[col * 3 + 2];
    float bc0 = b_conv[col];
    int e2 = 2048 + col;
    float c20 = w_conv[e2 * 3 + 0], c21 = w_conv[e2 * 3 + 1], c22 = w_conv[e2 * 3 + 2];
    float bc2 = b_conv[e2];

    size_t base = ((size_t)b * 4096 + l0) * 1024 + col;
    float p01 = (l0 >= 1) ? (float)u0[base - 1024] : 0.f;
    float p02 = (l0 >= 2) ? (float)u0[base - 2048] : 0.f;
    float p21 = (l0 >= 1) ? (float)u2[base - 1024] : 0.f;
    float p22 = (l0 >= 2) ? (float)u2[base - 2048] : 0.f;
    #pragma unroll
    for (int il = 0; il < 16; ++il) {
        float c0v = (float)u0[base + (size_t)il * 1024];
        float c2v = (float)u2[base + (size_t)il * 1024];
        float s0v = c00 * p02 + c01 * p01 + c02 * c0v + bc0;
        float s2v = c20 * p22 + c21 * p21 + c22 * c2v + bc2;
        p02 = p01; p01 = c0v; p22 = p21; p21 = c2v;
        vt[lg * 16 + il][d] = s0v * s2v;
        st[base + (size_t)il * 1024] = (__bf16)s0v;   // [B,L,D] direct, coalesced
    }
    __syncthreads();
    int lo = t & 63, dg = t >> 6;
    size_t obase = ((size_t)b * 1024 + d0 + dg * 16) * 4096 + l0b + lo;
    #pragma unroll
    for (int id = 0; id < 16; ++id)
        v[obase + (size_t)id * 4096] = (__bf16)vt[lo][dg * 16 + id];
}

// ---------------- K3: 1024-tap causal FIR via MFMA block-Toeplitz -------------
__global__ __launch_bounds__(256) void firk(const __bf16* __restrict__ v,
                                            const __bf16* __restrict__ afg,
                                            const float* __restrict__ filt_bias,
                                            __bf16* __restrict__ z) {
    __shared__ __bf16 vlds[768 * 8];       // chunks 0..129 zero-pad, 130..641 data
    __shared__ __bf16 alds[33 * 64 * 8];   // A-fragments, lane-contiguous
    int t = threadIdx.x;
    int bd = blockIdx.x;          // b*1024 + d
    int d = bd & 1023;
    const __bf16* vrow = v + (size_t)bd * 4096;

    for (int c = t; c < 33 * 64; c += 256)
        *(bf16x8*)&alds[c * 8] = *(const bf16x8*)&afg[(size_t)c * 8];
    #pragma unroll
    for (int i = 0; i < 3; ++i) {
        int c = t + i * 256;
        bf16x8 val = {};
        if (c >= 130 && c < 642) val = *(const bf16x8*)&vrow[(c - 130) * 8];
        int cs = c ^ ((c >> 3) & 7);
        *(bf16x8*)&vlds[cs * 8] = val;
    }
    __syncthreads();

    int lane = t & 63, w = t >> 6;
    int n = lane & 15, kh = lane >> 4;
    int khoff = (kh == 0) ? 0 : (kh == 1) ? 8 : (kh == 2) ? -16 : -8;
    f32x4 acc[4] = {};
    for (int sp = 0; sp < 33; ++sp) {
        bf16x8 af = *(const bf16x8*)&alds[(sp * 64 + lane) * 8];
        #pragma unroll
        for (int ct = 0; ct < 4; ++ct) {
            int p = w * 64 + ct * 16 + n;
            int e = 16 * p - 32 * sp + 1040 + khoff;   // vpad index, multiple of 8
            int c = e >> 3;
            int cs = c ^ ((c >> 3) & 7);
            bf16x8 bfv = *(const bf16x8*)&vlds[cs * 8];
            acc[ct] = __builtin_amdgcn_mfma_f32_16x16x32_bf16(af, bfv, acc[ct], 0, 0, 0);
        }
    }

    float fb = filt_bias[d];
    __bf16* zrow = z + (size_t)bd * 4096;
    #pragma unroll
    for (int ct = 0; ct < 4; ++ct) {
        int p = w * 64 + ct * 16 + n;
        #pragma unroll
        for (int j = 0; j < 4; ++j) {
            int l = 16 * p + kh * 4 + j;
            int e = l + 1040;
            int c = e >> 3;
            int cs = c ^ ((c >> 3) & 7);
            float vv = (float)vlds[cs * 8 + (e & 7)];
            zrow[l] = (__bf16)(acc[ct][j] + vv * fb);
        }
    }
}

// ---------------- K3b: transpose zz [B,D,L] -> [B,L,D] and gate by s0 ---------
__global__ __launch_bounds__(256) void trz(const __bf16* __restrict__ zz,
                                           const __bf16* __restrict__ st,
                                           __bf16* __restrict__ zt) {
    __shared__ __bf16 tile[64][65];
    int t = threadIdx.x;
    int l0 = blockIdx.x * 64, d0 = blockIdx.y * 64, b = blockIdx.z;
    int c = t & 63, rg = t >> 6;
    #pragma unroll
    for (int i = 0; i < 16; ++i) {
        int r = rg * 16 + i;
        tile[r][c] = zz[((size_t)(b * 1024 + d0 + r)) * 4096 + l0 + c];
    }
    __syncthreads();
    #pragma unroll
    for (int i = 0; i < 16; ++i) {
        int li = rg * 16 + i;
        size_t o = ((size_t)b * 4096 + l0 + li) * 1024 + d0 + c;
        zt[o] = (__bf16)((float)tile[c][li] * (float)st[o]);
    }
}

extern "C" void kernel_launch(void* const* d_in, const int* in_sizes, int n_in,
                              void* d_out, int out_size, void* d_ws, size_t ws_size,
                              hipStream_t stream) {
    const float* x      = (const float*)d_in[0];
    const float* w_in   = (const float*)d_in[1];
    const float* b_in   = (const float*)d_in[2];
    const float* w_conv = (const float*)d_in[3];
    const float* b_conv = (const float*)d_in[4];
    // d_in[5] = w1: multiplied by t[0]==0, mathematically unused for h
    const float* b1     = (const float*)d_in[6];
    const float* w2     = (const float*)d_in[7];
    const float* b2     = (const float*)d_in[8];
    const float* w3     = (const float*)d_in[9];
    const float* fb     = (const float*)d_in[10];
    const float* w_out  = (const float*)d_in[11];
    const float* b_out  = (const float*)d_in[12];
    float* out = (float*)d_out;

    // Workspace span = 40960 + 64 MB (round-1-proven bound), temporally aliased:
    //   X : xbf (P1) -> vv (P2-P3) -> wot (P5)
    //   U0: u0  (P1-P2) -> zt (P4-P5)
    //   U2: u2  (P1-P2) -> zz (P3-P4)
    //   ST: st  (P2...) ; WT overlaps ST's tail (WT dead before st written)
    char* ws = (char*)d_ws;
    __bf16* af = (__bf16*)(ws + 4096);                // 33 KB
    const size_t SEG = (size_t)8192 * 1024;
    __bf16* X  = (__bf16*)(ws + 40960);
    __bf16* U0 = X + SEG;
    __bf16* U2 = U0 + SEG;
    __bf16* ST = U2 + SEG;
    __bf16* WT = ST + SEG - (size_t)2048 * 1024;      // [2048][1024] bf16, 4 MB

    hgen<<<1, 256, 0, stream>>>(b1, w2, b2, w3, af);
    cvt_x<<<4096, 256, 0, stream>>>(x, X);
    tcvt<<<dim3(16, 16), 256, 0, stream>>>(w_in, WT, 3072, 0);
    tcvt<<<dim3(16, 16), 256, 0, stream>>>(w_in, WT + (size_t)1024 * 1024, 3072, 2048);
    gemm256<<<dim3(32, 8), 512, 0, stream>>>(X, WT, b_in, U0, U2);
    convmul<<<dim3(64, 16, 2), 256, 0, stream>>>(U0, U2, w_conv, b_conv, X, ST);
    firk<<<2048, 256, 0, stream>>>(X, af, fb, U2);
    tcvt<<<dim3(16, 16), 256, 0, stream>>>(w_out, X, 1024, 0);   // wot into X (vv dead)
    trz<<<dim3(64, 16, 2), 256, 0, stream>>>(U2, ST, U0);
    gemm128<<<dim3(64, 8), 256, 0, stream>>>(U0, X, b_out, out);
}